// Round 1
// baseline (523.921 us; speedup 1.0000x reference)
//
#include <hip/hip_runtime.h>
#include <stdint.h>

#define BATCH 8192
#define DIM   1024

typedef __bf16 bf16x8  __attribute__((ext_vector_type(8)));
typedef float  floatx4 __attribute__((ext_vector_type(4)));

__device__ __forceinline__ unsigned short f2bf(float x) {
    union { float f; unsigned int u; } v; v.f = x;
    unsigned int r = v.u + 0x7fffu + ((v.u >> 16) & 1u);   // RNE
    return (unsigned short)(r >> 16);
}

__device__ __forceinline__ void async_ld16(const void* g, void* l) {
    __builtin_amdgcn_global_load_lds(
        (__attribute__((address_space(1))) void*)(void*)g,
        (__attribute__((address_space(3))) void*)l,
        16, 0, 0);
}

// ---------------- row L2-normalize: fp32 -> bf16 ----------------
__global__ __launch_bounds__(256) void norm_kernel(const float* __restrict__ in,
                                                   unsigned short* __restrict__ out) {
    const int row = blockIdx.x;
    const int t   = threadIdx.x;
    const float4* src = (const float4*)(in + (size_t)row * DIM);
    float4 v = src[t];
    float ss = v.x * v.x + v.y * v.y + v.z * v.z + v.w * v.w;
    #pragma unroll
    for (int m = 32; m >= 1; m >>= 1) ss += __shfl_xor(ss, m);
    __shared__ float red[4];
    if ((t & 63) == 0) red[t >> 6] = ss;
    __syncthreads();
    const float n2  = red[0] + red[1] + red[2] + red[3];
    const float inv = 1.0f / fmaxf(sqrtf(n2), 1e-12f);
    ushort4 o;
    o.x = f2bf(v.x * inv);
    o.y = f2bf(v.y * inv);
    o.z = f2bf(v.z * inv);
    o.w = f2bf(v.w * inv);
    ((ushort4*)(out + (size_t)row * DIM))[t] = o;
}

// ---------------- fused sim GEMM + exp + masked row-sum ----------------
// C[i][j] = f_i . f_j  (both from the same normalized matrix, gemm_bt layout)
// Accumulate exp(2*C[i][j]) into SR[i] (label[j]!=0) or SN[i] (label[j]==0),
// skipping j==i (the reference's eye mask).
__global__ __launch_bounds__(256) void sim_kernel(const unsigned short* __restrict__ F,
                                                  const int* __restrict__ label,
                                                  float* __restrict__ S) {
    const int f = blockIdx.z;
    const unsigned short* A = F + (size_t)f * BATCH * DIM;
    float* SR = S + (size_t)f * 2 * BATCH;
    float* SN = SR + BATCH;

    __shared__ __align__(16) unsigned short As[128 * 32];
    __shared__ __align__(16) unsigned short Bs[128 * 32];

    const int tid  = threadIdx.x;
    const int lane = tid & 63;
    const int wave = tid >> 6;
    const int wm   = wave >> 1;        // 2x2 wave grid over the 128x128 tile
    const int wn   = wave & 1;
    const int quad = lane >> 4;
    const int cl   = lane & 15;

    const int rowTile = blockIdx.y * 128;
    const int colTile = blockIdx.x * 128;

    // global->LDS staging: each wave covers 32 rows via 2 issues of 16 rows;
    // lane l -> row l/4, 16B chunk (l&3)*8 elements. Matches HW lane*16 LDS scatter.
    const int sRow = wave * 32 + (lane >> 2);
    const int kOff = (lane & 3) * 8;
    const unsigned short* gA0 = A + (size_t)(rowTile + sRow) * DIM + kOff;
    const unsigned short* gA1 = gA0 + 16 * DIM;
    const unsigned short* gB0 = A + (size_t)(colTile + sRow) * DIM + kOff;
    const unsigned short* gB1 = gB0 + 16 * DIM;

    unsigned short* lA0 = As + wave * 32 * 32;
    unsigned short* lA1 = lA0 + 16 * 32;
    unsigned short* lB0 = Bs + wave * 32 * 32;
    unsigned short* lB1 = lB0 + 16 * 32;

    floatx4 acc[4][4];
    const floatx4 z4 = {0.f, 0.f, 0.f, 0.f};
    #pragma unroll
    for (int mi = 0; mi < 4; ++mi)
        #pragma unroll
        for (int ni = 0; ni < 4; ++ni) acc[mi][ni] = z4;

    // MFMA A/B operand: lane holds [m|n = lane&15][k = quad*8 .. +8]
    const unsigned short* aFragBase = As + (wm * 64 + cl) * 32 + quad * 8;
    const unsigned short* bFragBase = Bs + (wn * 64 + cl) * 32 + quad * 8;

    for (int k0 = 0; k0 < DIM; k0 += 32) {
        __syncthreads();                 // all waves done reading previous tile
        async_ld16(gA0, lA0);
        async_ld16(gA1, lA1);
        async_ld16(gB0, lB0);
        async_ld16(gB1, lB1);
        gA0 += 32; gA1 += 32; gB0 += 32; gB1 += 32;
        __syncthreads();                 // vmcnt drain + all data visible

        bf16x8 af[4], bfr[4];
        #pragma unroll
        for (int mi = 0; mi < 4; ++mi)
            af[mi] = *(const bf16x8*)(aFragBase + mi * 16 * 32);
        #pragma unroll
        for (int ni = 0; ni < 4; ++ni)
            bfr[ni] = *(const bf16x8*)(bFragBase + ni * 16 * 32);
        #pragma unroll
        for (int mi = 0; mi < 4; ++mi)
            #pragma unroll
            for (int ni = 0; ni < 4; ++ni)
                acc[mi][ni] = __builtin_amdgcn_mfma_f32_16x16x32_bf16(
                    af[mi], bfr[ni], acc[mi][ni], 0, 0, 0);
    }

    // ---- epilogue: exp(2c), mask diag, split by label[col], reduce per row ----
    int   colg[4];
    float wR[4];
    #pragma unroll
    for (int ni = 0; ni < 4; ++ni) {
        colg[ni] = colTile + wn * 64 + ni * 16 + cl;
        wR[ni]   = (label[colg[ni]] != 0) ? 1.0f : 0.0f;
    }
    #pragma unroll
    for (int mi = 0; mi < 4; ++mi) {
        const int rowBase = rowTile + wm * 64 + mi * 16 + quad * 4;   // C/D: row=quad*4+reg
        #pragma unroll
        for (int r = 0; r < 4; ++r) {
            const int rowg = rowBase + r;
            float pR = 0.f, pN = 0.f;
            #pragma unroll
            for (int ni = 0; ni < 4; ++ni) {
                float c = acc[mi][ni][r];
                float e = __expf(2.0f * c);
                e = (rowg == colg[ni]) ? 0.0f : e;   // eye mask
                pR += wR[ni] * e;
                pN += (1.0f - wR[ni]) * e;
            }
            // sum over the 16 lanes of this quad (cols 0..15 of each frag)
            #pragma unroll
            for (int m = 1; m < 16; m <<= 1) {
                pR += __shfl_xor(pR, m);
                pN += __shfl_xor(pN, m);
            }
            if (cl == 0) {
                atomicAdd(&SR[rowg], pR);
                atomicAdd(&SN[rowg], pN);
            }
        }
    }
}

// ---------------- final per-row loss + global reduce ----------------
__global__ __launch_bounds__(256) void loss_kernel(const float* __restrict__ S,
                                                   const int* __restrict__ label,
                                                   float* __restrict__ out) {
    const int i = blockIdx.x * 256 + threadIdx.x;   // 0..8191
    const int lab = label[i];
    float t = 0.f;
    #pragma unroll
    for (int f = 0; f < 2; ++f) {
        const float* SR = S + (size_t)f * 2 * BATCH;
        const float* SN = SR + BATCH;
        const float own = lab ? SR[i] : SN[i];
        const float oth = lab ? SN[i] : SR[i];
        t += -logf(own / (own + oth) + 1e-8f);
    }
    t *= (1.0f / 4096.0f);
    #pragma unroll
    for (int m = 32; m >= 1; m >>= 1) t += __shfl_xor(t, m);
    __shared__ float red[4];
    if ((threadIdx.x & 63) == 0) red[threadIdx.x >> 6] = t;
    __syncthreads();
    if (threadIdx.x == 0) atomicAdd(out, red[0] + red[1] + red[2] + red[3]);
}

extern "C" void kernel_launch(void* const* d_in, const int* in_sizes, int n_in,
                              void* d_out, int out_size, void* d_ws, size_t ws_size,
                              hipStream_t stream) {
    const float* text  = (const float*)d_in[0];
    const float* image = (const float*)d_in[1];
    const int*   label = (const int*)d_in[2];
    float* out = (float*)d_out;

    // workspace layout: Fn[2][8192][1024] bf16 (32 MB), then S[2][2][8192] f32
    unsigned short* Fn = (unsigned short*)d_ws;
    float* S = (float*)((char*)d_ws + (size_t)2 * BATCH * DIM * sizeof(unsigned short));

    hipMemsetAsync(S, 0, (size_t)2 * 2 * BATCH * sizeof(float), stream);
    hipMemsetAsync(out, 0, sizeof(float), stream);

    norm_kernel<<<BATCH, 256, 0, stream>>>(text,  Fn);
    norm_kernel<<<BATCH, 256, 0, stream>>>(image, Fn + (size_t)BATCH * DIM);

    dim3 grid(BATCH / 128, BATCH / 128, 2);
    sim_kernel<<<grid, 256, 0, stream>>>(Fn, label, S);

    loss_kernel<<<BATCH / 256, 256, 0, stream>>>(S, label, out);
}

// Round 2
// 399.450 us; speedup vs baseline: 1.3116x; 1.3116x over previous
//
#include <hip/hip_runtime.h>
#include <stdint.h>

#define BATCH 8192
#define DIM   1024
#define NTILE 64              // 8192 / 128 tiles per dimension
#define NTRI  (NTILE * (NTILE + 1) / 2)   // 2080 upper-triangle tiles

typedef __bf16 bf16x8  __attribute__((ext_vector_type(8)));
typedef float  floatx4 __attribute__((ext_vector_type(4)));

__device__ __forceinline__ unsigned short f2bf(float x) {
    union { float f; unsigned int u; } v; v.f = x;
    unsigned int r = v.u + 0x7fffu + ((v.u >> 16) & 1u);   // RNE
    return (unsigned short)(r >> 16);
}

__device__ __forceinline__ void async_ld16(const void* g, void* l) {
    __builtin_amdgcn_global_load_lds(
        (__attribute__((address_space(1))) void*)(void*)g,
        (__attribute__((address_space(3))) void*)l,
        16, 0, 0);
}

// ---------------- row L2-normalize: fp32 -> bf16 (both features) ----------------
__global__ __launch_bounds__(256) void norm_kernel(const float* __restrict__ text,
                                                   const float* __restrict__ image,
                                                   unsigned short* __restrict__ out) {
    const int fsel = blockIdx.y;
    const float* in = fsel ? image : text;
    unsigned short* o = out + (size_t)fsel * BATCH * DIM;
    const int row = blockIdx.x;
    const int t   = threadIdx.x;
    const float4* src = (const float4*)(in + (size_t)row * DIM);
    float4 v = src[t];
    float ss = v.x * v.x + v.y * v.y + v.z * v.z + v.w * v.w;
    #pragma unroll
    for (int m = 32; m >= 1; m >>= 1) ss += __shfl_xor(ss, m);
    __shared__ float red[4];
    if ((t & 63) == 0) red[t >> 6] = ss;
    __syncthreads();
    const float n2  = red[0] + red[1] + red[2] + red[3];
    const float inv = 1.0f / fmaxf(sqrtf(n2), 1e-12f);
    ushort4 ov;
    ov.x = f2bf(v.x * inv);
    ov.y = f2bf(v.y * inv);
    ov.z = f2bf(v.z * inv);
    ov.w = f2bf(v.w * inv);
    ((ushort4*)(o + (size_t)row * DIM))[t] = ov;
}

// -------- fused symmetric sim GEMM + exp + masked dual row/col-sum --------
// Upper-triangle tiles only (bi <= bj). For each tile: C = A_bi . A_bj^T.
// Row part: SR/SN[row i] += exp(2c) bucketed by label[col j] (diag masked on bi==bj).
// Col part (bi<bj only, via symmetry): SR/SN[col j] += exp(2c) bucketed by label[row i].
__global__ __launch_bounds__(256) void sim_kernel(const unsigned short* __restrict__ F,
                                                  const int* __restrict__ label,
                                                  float* __restrict__ S) {
    const int f = blockIdx.z;
    const unsigned short* A = F + (size_t)f * BATCH * DIM;
    float* SR = S + (size_t)f * 2 * BATCH;
    float* SN = SR + BATCH;

    // triangular tile decode: row bi owns (NTILE - bi) tiles
    int rem = blockIdx.x, bi = 0;
    while (rem >= NTILE - bi) { rem -= NTILE - bi; ++bi; }
    const int bj = bi + rem;
    const bool diag = (bi == bj);

    const int rowTile = bi * 128;
    const int colTile = bj * 128;

    __shared__ __align__(16) unsigned short As[128 * 32];
    __shared__ __align__(16) unsigned short Bs[128 * 32];

    const int tid  = threadIdx.x;
    const int lane = tid & 63;
    const int wave = tid >> 6;
    const int wm   = wave >> 1;        // 2x2 wave grid over the 128x128 tile
    const int wn   = wave & 1;
    const int quad = lane >> 4;
    const int cl   = lane & 15;

    // global->LDS staging with XOR chunk swizzle to kill ds_read_b128 bank
    // conflicts: slot s of row r holds global chunk s ^ ((r>>1)&3).
    const int sRow     = wave * 32 + (lane >> 2);
    const int chunkSel = (lane & 3) ^ ((lane >> 3) & 3);   // ((sRow>>1)&3 == (lane>>3)&3)
    const int kOff     = chunkSel * 8;
    const unsigned short* gA0 = A + (size_t)(rowTile + sRow) * DIM + kOff;
    const unsigned short* gA1 = gA0 + 16 * DIM;
    const unsigned short* gB0 = A + (size_t)(colTile + sRow) * DIM + kOff;
    const unsigned short* gB1 = gB0 + 16 * DIM;

    unsigned short* lA0 = As + wave * 32 * 32;
    unsigned short* lA1 = lA0 + 16 * 32;
    unsigned short* lB0 = Bs + wave * 32 * 32;
    unsigned short* lB1 = lB0 + 16 * 32;

    floatx4 acc[4][4];
    const floatx4 z4 = {0.f, 0.f, 0.f, 0.f};
    #pragma unroll
    for (int mi = 0; mi < 4; ++mi)
        #pragma unroll
        for (int ni = 0; ni < 4; ++ni) acc[mi][ni] = z4;

    // fragment read: un-swizzle -> slot (quad ^ ((cl>>1)&3))
    const int swzOff = ((quad ^ ((cl >> 1) & 3)) * 8);
    const unsigned short* aFragBase = As + (wm * 64 + cl) * 32 + swzOff;
    const unsigned short* bFragBase = Bs + (wn * 64 + cl) * 32 + swzOff;

    for (int k0 = 0; k0 < DIM; k0 += 32) {
        __syncthreads();                 // all waves done reading previous tile
        async_ld16(gA0, lA0);
        async_ld16(gA1, lA1);
        async_ld16(gB0, lB0);
        async_ld16(gB1, lB1);
        gA0 += 32; gA1 += 32; gB0 += 32; gB1 += 32;
        __syncthreads();                 // vmcnt drain + all data visible

        bf16x8 af[4], bfr[4];
        #pragma unroll
        for (int mi = 0; mi < 4; ++mi)
            af[mi] = *(const bf16x8*)(aFragBase + mi * 16 * 32);
        #pragma unroll
        for (int ni = 0; ni < 4; ++ni)
            bfr[ni] = *(const bf16x8*)(bFragBase + ni * 16 * 32);
        #pragma unroll
        for (int mi = 0; mi < 4; ++mi)
            #pragma unroll
            for (int ni = 0; ni < 4; ++ni)
                acc[mi][ni] = __builtin_amdgcn_mfma_f32_16x16x32_bf16(
                    af[mi], bfr[ni], acc[mi][ni], 0, 0, 0);
    }

    // ---- epilogue ----
    int   colg[4];
    float wRc[4];                        // col label weight (row-part bucket)
    #pragma unroll
    for (int ni = 0; ni < 4; ++ni) {
        colg[ni] = colTile + wn * 64 + ni * 16 + cl;
        wRc[ni]  = (label[colg[ni]] != 0) ? 1.0f : 0.0f;
    }

    float colR[4] = {0.f, 0.f, 0.f, 0.f};
    float colN[4] = {0.f, 0.f, 0.f, 0.f};

    #pragma unroll
    for (int mi = 0; mi < 4; ++mi) {
        const int rowBase = rowTile + wm * 64 + mi * 16 + quad * 4;   // C/D: row=quad*4+reg
        #pragma unroll
        for (int r = 0; r < 4; ++r) {
            const int rowg = rowBase + r;
            const float wRr = (label[rowg] != 0) ? 1.0f : 0.0f;  // row label (col-part bucket)
            float pR = 0.f, pN = 0.f;
            #pragma unroll
            for (int ni = 0; ni < 4; ++ni) {
                float c = acc[mi][ni][r];
                float e = __expf(2.0f * c);
                if (diag) e = (rowg == colg[ni]) ? 0.0f : e;      // eye mask
                pR += wRc[ni] * e;
                pN += (1.0f - wRc[ni]) * e;
                colR[ni] += wRr * e;
                colN[ni] += (1.0f - wRr) * e;
            }
            // sum over the 16 lanes of this quad (16 cols of each frag)
            #pragma unroll
            for (int m = 1; m < 16; m <<= 1) {
                pR += __shfl_xor(pR, m);
                pN += __shfl_xor(pN, m);
            }
            if (cl == 0) {
                atomicAdd(&SR[rowg], pR);
                atomicAdd(&SN[rowg], pN);
            }
        }
    }

    if (!diag) {
        // column part: reduce over the 4 quads (rows) then commit per col
        #pragma unroll
        for (int ni = 0; ni < 4; ++ni) {
            float cR = colR[ni], cN = colN[ni];
            cR += __shfl_xor(cR, 16); cN += __shfl_xor(cN, 16);
            cR += __shfl_xor(cR, 32); cN += __shfl_xor(cN, 32);
            if (quad == 0) {
                atomicAdd(&SR[colg[ni]], cR);
                atomicAdd(&SN[colg[ni]], cN);
            }
        }
    }
}

// ---------------- final per-row loss + global reduce ----------------
__global__ __launch_bounds__(256) void loss_kernel(const float* __restrict__ S,
                                                   const int* __restrict__ label,
                                                   float* __restrict__ out) {
    const int i = blockIdx.x * 256 + threadIdx.x;   // 0..8191
    const int lab = label[i];
    float t = 0.f;
    #pragma unroll
    for (int f = 0; f < 2; ++f) {
        const float* SR = S + (size_t)f * 2 * BATCH;
        const float* SN = SR + BATCH;
        const float own = lab ? SR[i] : SN[i];
        const float oth = lab ? SN[i] : SR[i];
        t += -logf(own / (own + oth) + 1e-8f);
    }
    t *= (1.0f / 4096.0f);
    #pragma unroll
    for (int m = 32; m >= 1; m >>= 1) t += __shfl_xor(t, m);
    __shared__ float red[4];
    if ((threadIdx.x & 63) == 0) red[threadIdx.x >> 6] = t;
    __syncthreads();
    if (threadIdx.x == 0) atomicAdd(out, red[0] + red[1] + red[2] + red[3]);
}

extern "C" void kernel_launch(void* const* d_in, const int* in_sizes, int n_in,
                              void* d_out, int out_size, void* d_ws, size_t ws_size,
                              hipStream_t stream) {
    const float* text  = (const float*)d_in[0];
    const float* image = (const float*)d_in[1];
    const int*   label = (const int*)d_in[2];
    float* out = (float*)d_out;

    // workspace layout: Fn[2][8192][1024] bf16 (32 MB), then S[2][2][8192] f32
    unsigned short* Fn = (unsigned short*)d_ws;
    float* S = (float*)((char*)d_ws + (size_t)2 * BATCH * DIM * sizeof(unsigned short));

    hipMemsetAsync(S, 0, (size_t)2 * 2 * BATCH * sizeof(float), stream);
    hipMemsetAsync(out, 0, sizeof(float), stream);

    dim3 ngrid(BATCH, 2);
    norm_kernel<<<ngrid, 256, 0, stream>>>(text, image, Fn);

    dim3 grid(NTRI, 1, 2);
    sim_kernel<<<grid, 256, 0, stream>>>(Fn, label, S);

    loss_kernel<<<BATCH / 256, 256, 0, stream>>>(S, label, out);
}

// Round 3
// 376.689 us; speedup vs baseline: 1.3909x; 1.0604x over previous
//
#include <hip/hip_runtime.h>
#include <stdint.h>

#define BATCH 8192
#define DIM   1024
#define NTILE 64              // 8192 / 128 tiles per dimension
#define MAXB  292             // max tiles per XCD band
#define GRIDX (8 * MAXB)      // padded x-grid; blocks past band size exit

typedef __bf16 bf16x8  __attribute__((ext_vector_type(8)));
typedef float  floatx4 __attribute__((ext_vector_type(4)));

__device__ __forceinline__ unsigned short f2bf(float x) {
    union { float f; unsigned int u; } v; v.f = x;
    unsigned int r = v.u + 0x7fffu + ((v.u >> 16) & 1u);   // RNE
    return (unsigned short)(r >> 16);
}

__device__ __forceinline__ void async_ld16(const void* g, void* l) {
    __builtin_amdgcn_global_load_lds(
        (__attribute__((address_space(1))) void*)(void*)g,
        (__attribute__((address_space(3))) void*)l,
        16, 0, 0);
}

// ---------------- row L2-normalize: fp32 -> bf16 (both features) ----------------
__global__ __launch_bounds__(256) void norm_kernel(const float* __restrict__ text,
                                                   const float* __restrict__ image,
                                                   unsigned short* __restrict__ out) {
    const int fsel = blockIdx.y;
    const float* in = fsel ? image : text;
    unsigned short* o = out + (size_t)fsel * BATCH * DIM;
    const int row = blockIdx.x;
    const int t   = threadIdx.x;
    const float4* src = (const float4*)(in + (size_t)row * DIM);
    float4 v = src[t];
    float ss = v.x * v.x + v.y * v.y + v.z * v.z + v.w * v.w;
    #pragma unroll
    for (int m = 32; m >= 1; m >>= 1) ss += __shfl_xor(ss, m);
    __shared__ float red[4];
    if ((t & 63) == 0) red[t >> 6] = ss;
    __syncthreads();
    const float n2  = red[0] + red[1] + red[2] + red[3];
    const float inv = 1.0f / fmaxf(sqrtf(n2), 1e-12f);
    ushort4 ov;
    ov.x = f2bf(v.x * inv);
    ov.y = f2bf(v.y * inv);
    ov.z = f2bf(v.z * inv);
    ov.w = f2bf(v.w * inv);
    ((ushort4*)(o + (size_t)row * DIM))[t] = ov;
}

// -------- fused symmetric sim GEMM + exp + masked dual row/col-sum --------
// Upper-triangle tiles, XCD-banded schedule: bj-columns partitioned into 8
// equal-area bands; band x runs on XCD x (blockIdx.x & 7). Within a band:
// bi-major, bj-fastest -> per-XCD L2 keeps the band's B panels + current A
// panel hot, so global_load_lds staging hits L2 instead of L3/HBM.
__global__ __launch_bounds__(256) void sim_kernel(const unsigned short* __restrict__ F,
                                                  const int* __restrict__ label,
                                                  float* __restrict__ S) {
    // band tables: bj in [bs[x], be[x]); bn[x] = tiles in band
    const int bs[8] = {0, 23, 32, 40, 46, 51, 56, 60};
    const int be[8] = {23, 32, 40, 46, 51, 56, 60, 64};
    const int bn[8] = {276, 252, 292, 261, 245, 270, 234, 250};

    const int x = blockIdx.x & 7;       // XCD (heuristic: round-robin dispatch)
    const int l = blockIdx.x >> 3;      // local index within band
    if (l >= bn[x]) return;             // padding block

    const int s = bs[x];
    const int w = be[x] - s;
    int bi, bj;
    const int nfull = s * w;            // rows bi < s: all w columns
    if (l < nfull) {
        bi = l / w;
        bj = s + (l % w);
    } else {
        int l2 = l - nfull;             // triangular remainder: row s+k has w-k tiles
        int k = 0, width = w;
        while (l2 >= width) { l2 -= width; --width; ++k; }
        bi = s + k;
        bj = bi + l2;
    }
    const bool diag = (bi == bj);

    const int f = blockIdx.z;
    const unsigned short* A = F + (size_t)f * BATCH * DIM;
    float* SR = S + (size_t)f * 2 * BATCH;
    float* SN = SR + BATCH;

    const int rowTile = bi * 128;
    const int colTile = bj * 128;

    __shared__ __align__(16) unsigned short As[128 * 32];
    __shared__ __align__(16) unsigned short Bs[128 * 32];

    const int tid  = threadIdx.x;
    const int lane = tid & 63;
    const int wave = tid >> 6;
    const int wm   = wave >> 1;        // 2x2 wave grid over the 128x128 tile
    const int wn   = wave & 1;
    const int quad = lane >> 4;
    const int cl   = lane & 15;

    // global->LDS staging with XOR chunk swizzle (bank-conflict-free frags):
    // slot s of row r holds global chunk s ^ ((r>>1)&3).
    const int sRow     = wave * 32 + (lane >> 2);
    const int chunkSel = (lane & 3) ^ ((lane >> 3) & 3);
    const int kOff     = chunkSel * 8;
    const unsigned short* gA0 = A + (size_t)(rowTile + sRow) * DIM + kOff;
    const unsigned short* gA1 = gA0 + 16 * DIM;
    const unsigned short* gB0 = A + (size_t)(colTile + sRow) * DIM + kOff;
    const unsigned short* gB1 = gB0 + 16 * DIM;

    unsigned short* lA0 = As + wave * 32 * 32;
    unsigned short* lA1 = lA0 + 16 * 32;
    unsigned short* lB0 = Bs + wave * 32 * 32;
    unsigned short* lB1 = lB0 + 16 * 32;

    floatx4 acc[4][4];
    const floatx4 z4 = {0.f, 0.f, 0.f, 0.f};
    #pragma unroll
    for (int mi = 0; mi < 4; ++mi)
        #pragma unroll
        for (int ni = 0; ni < 4; ++ni) acc[mi][ni] = z4;

    // fragment read: un-swizzle -> slot (quad ^ ((cl>>1)&3))
    const int swzOff = ((quad ^ ((cl >> 1) & 3)) * 8);
    const unsigned short* aFragBase = As + (wm * 64 + cl) * 32 + swzOff;
    const unsigned short* bFragBase = Bs + (wn * 64 + cl) * 32 + swzOff;

    for (int k0 = 0; k0 < DIM; k0 += 32) {
        __syncthreads();                 // all waves done reading previous tile
        async_ld16(gA0, lA0);
        async_ld16(gA1, lA1);
        async_ld16(gB0, lB0);
        async_ld16(gB1, lB1);
        gA0 += 32; gA1 += 32; gB0 += 32; gB1 += 32;
        __syncthreads();                 // vmcnt drain + all data visible

        bf16x8 af[4], bfr[4];
        #pragma unroll
        for (int mi = 0; mi < 4; ++mi)
            af[mi] = *(const bf16x8*)(aFragBase + mi * 16 * 32);
        #pragma unroll
        for (int ni = 0; ni < 4; ++ni)
            bfr[ni] = *(const bf16x8*)(bFragBase + ni * 16 * 32);
        #pragma unroll
        for (int mi = 0; mi < 4; ++mi)
            #pragma unroll
            for (int ni = 0; ni < 4; ++ni)
                acc[mi][ni] = __builtin_amdgcn_mfma_f32_16x16x32_bf16(
                    af[mi], bfr[ni], acc[mi][ni], 0, 0, 0);
    }

    // ---- epilogue ----
    int   colg[4];
    float wRc[4];                        // col label weight (row-part bucket)
    #pragma unroll
    for (int ni = 0; ni < 4; ++ni) {
        colg[ni] = colTile + wn * 64 + ni * 16 + cl;
        wRc[ni]  = (label[colg[ni]] != 0) ? 1.0f : 0.0f;
    }

    float colR[4] = {0.f, 0.f, 0.f, 0.f};
    float colN[4] = {0.f, 0.f, 0.f, 0.f};

    #pragma unroll
    for (int mi = 0; mi < 4; ++mi) {
        const int rowBase = rowTile + wm * 64 + mi * 16 + quad * 4;   // C/D: row=quad*4+reg
        #pragma unroll
        for (int r = 0; r < 4; ++r) {
            const int rowg = rowBase + r;
            const float wRr = (label[rowg] != 0) ? 1.0f : 0.0f;  // row label (col-part bucket)
            float pR = 0.f, pN = 0.f;
            #pragma unroll
            for (int ni = 0; ni < 4; ++ni) {
                float c = acc[mi][ni][r];
                float e = __expf(2.0f * c);
                if (diag) e = (rowg == colg[ni]) ? 0.0f : e;      // eye mask
                pR += wRc[ni] * e;
                pN += (1.0f - wRc[ni]) * e;
                colR[ni] += wRr * e;
                colN[ni] += (1.0f - wRr) * e;
            }
            // sum over the 16 lanes of this quad (16 cols of each frag)
            #pragma unroll
            for (int m = 1; m < 16; m <<= 1) {
                pR += __shfl_xor(pR, m);
                pN += __shfl_xor(pN, m);
            }
            if (cl == 0) {
                atomicAdd(&SR[rowg], pR);
                atomicAdd(&SN[rowg], pN);
            }
        }
    }

    if (!diag) {
        // column part: reduce over the 4 quads (rows) then commit per col
        #pragma unroll
        for (int ni = 0; ni < 4; ++ni) {
            float cR = colR[ni], cN = colN[ni];
            cR += __shfl_xor(cR, 16); cN += __shfl_xor(cN, 16);
            cR += __shfl_xor(cR, 32); cN += __shfl_xor(cN, 32);
            if (quad == 0) {
                atomicAdd(&SR[colg[ni]], cR);
                atomicAdd(&SN[colg[ni]], cN);
            }
        }
    }
}

// ---------------- final per-row loss + global reduce ----------------
__global__ __launch_bounds__(256) void loss_kernel(const float* __restrict__ S,
                                                   const int* __restrict__ label,
                                                   float* __restrict__ out) {
    const int i = blockIdx.x * 256 + threadIdx.x;   // 0..8191
    const int lab = label[i];
    float t = 0.f;
    #pragma unroll
    for (int f = 0; f < 2; ++f) {
        const float* SR = S + (size_t)f * 2 * BATCH;
        const float* SN = SR + BATCH;
        const float own = lab ? SR[i] : SN[i];
        const float oth = lab ? SN[i] : SR[i];
        t += -logf(own / (own + oth) + 1e-8f);
    }
    t *= (1.0f / 4096.0f);
    #pragma unroll
    for (int m = 32; m >= 1; m >>= 1) t += __shfl_xor(t, m);
    __shared__ float red[4];
    if ((threadIdx.x & 63) == 0) red[threadIdx.x >> 6] = t;
    __syncthreads();
    if (threadIdx.x == 0) atomicAdd(out, red[0] + red[1] + red[2] + red[3]);
}

extern "C" void kernel_launch(void* const* d_in, const int* in_sizes, int n_in,
                              void* d_out, int out_size, void* d_ws, size_t ws_size,
                              hipStream_t stream) {
    const float* text  = (const float*)d_in[0];
    const float* image = (const float*)d_in[1];
    const int*   label = (const int*)d_in[2];
    float* out = (float*)d_out;

    // workspace layout: Fn[2][8192][1024] bf16 (32 MB), then S[2][2][8192] f32
    unsigned short* Fn = (unsigned short*)d_ws;
    float* S = (float*)((char*)d_ws + (size_t)2 * BATCH * DIM * sizeof(unsigned short));

    hipMemsetAsync(S, 0, (size_t)2 * 2 * BATCH * sizeof(float), stream);
    hipMemsetAsync(out, 0, sizeof(float), stream);

    dim3 ngrid(BATCH, 2);
    norm_kernel<<<ngrid, 256, 0, stream>>>(text, image, Fn);

    dim3 grid(GRIDX, 1, 2);
    sim_kernel<<<grid, 256, 0, stream>>>(Fn, label, S);

    loss_kernel<<<BATCH / 256, 256, 0, stream>>>(S, label, out);
}

// Round 4
// 341.060 us; speedup vs baseline: 1.5362x; 1.1045x over previous
//
#include <hip/hip_runtime.h>
#include <stdint.h>

#define BATCH 8192
#define DIM   1024            // elements per row; fp8 => also bytes per row
#define NTILE 64              // 8192 / 128 tiles per dimension
#define MAXB  292             // max tiles per XCD band
#define GRIDX (8 * MAXB)      // padded x-grid; blocks past band size exit

#define FSCALE 8.0f                          // pre-scale before fp8 quant
#define EXPF   (2.0f / (FSCALE * FSCALE))    // exp(2*dot) = exp(acc * EXPF)

typedef int   intx4   __attribute__((ext_vector_type(4)));
typedef int   intx8   __attribute__((ext_vector_type(8)));
typedef float floatx4 __attribute__((ext_vector_type(4)));

__device__ __forceinline__ void async_ld16(const void* g, void* l) {
    __builtin_amdgcn_global_load_lds(
        (__attribute__((address_space(1))) void*)(void*)g,
        (__attribute__((address_space(3))) void*)l,
        16, 0, 0);
}

// ------------- row L2-normalize: fp32 -> fp8 e4m3 (x FSCALE) -------------
__global__ __launch_bounds__(256) void norm_kernel(const float* __restrict__ text,
                                                   const float* __restrict__ image,
                                                   unsigned char* __restrict__ out) {
    const int fsel = blockIdx.y;
    const float* in = fsel ? image : text;
    unsigned char* o = out + (size_t)fsel * BATCH * DIM;
    const int row = blockIdx.x;
    const int t   = threadIdx.x;
    const float4* src = (const float4*)(in + (size_t)row * DIM);
    float4 v = src[t];
    float ss = v.x * v.x + v.y * v.y + v.z * v.z + v.w * v.w;
    #pragma unroll
    for (int m = 32; m >= 1; m >>= 1) ss += __shfl_xor(ss, m);
    __shared__ float red[4];
    if ((t & 63) == 0) red[t >> 6] = ss;
    __syncthreads();
    const float n2  = red[0] + red[1] + red[2] + red[3];
    const float inv = FSCALE / fmaxf(sqrtf(n2), 1e-12f);
    // pack 4 e4m3 bytes (gfx950: OCP e4m3fn), byte i = element t*4+i
    int p = __builtin_amdgcn_cvt_pk_fp8_f32(v.x * inv, v.y * inv, 0, false);
    p     = __builtin_amdgcn_cvt_pk_fp8_f32(v.z * inv, v.w * inv, p, true);
    ((int*)(o + (size_t)row * DIM))[t] = p;
}

// -------- fused symmetric sim GEMM (MX-fp8, unit scales) + exp + dual sum --------
// Upper-triangle tiles, XCD-banded schedule (round-3 proven). BK=128 via
// mfma_scale_f32_16x16x128_f8f6f4 with all scales = 2^0 -> plain fp8 dot.
// 8 K-iters per block (vs 32 bf16) -> 4x fewer barrier drains.
__global__ __launch_bounds__(256) void sim_kernel(const unsigned char* __restrict__ F,
                                                  const int* __restrict__ label,
                                                  float* __restrict__ S) {
    // band tables: bj in [bs[x], be[x]); bn[x] = tiles in band
    const int bs[8] = {0, 23, 32, 40, 46, 51, 56, 60};
    const int be[8] = {23, 32, 40, 46, 51, 56, 60, 64};
    const int bn[8] = {276, 252, 292, 261, 245, 270, 234, 250};

    const int x = blockIdx.x & 7;       // XCD (round-robin dispatch heuristic)
    const int l = blockIdx.x >> 3;      // local index within band
    if (l >= bn[x]) return;             // padding block

    const int s = bs[x];
    const int w = be[x] - s;
    int bi, bj;
    const int nfull = s * w;
    if (l < nfull) {
        bi = l / w;
        bj = s + (l % w);
    } else {
        int l2 = l - nfull;
        int k = 0, width = w;
        while (l2 >= width) { l2 -= width; --width; ++k; }
        bi = s + k;
        bj = bi + l2;
    }
    const bool diag = (bi == bj);

    const int f = blockIdx.z;
    const unsigned char* A = F + (size_t)f * BATCH * DIM;
    float* SR = S + (size_t)f * 2 * BATCH;
    float* SN = SR + BATCH;

    const int rowTile = bi * 128;
    const int colTile = bj * 128;

    // 128 rows x 128 K-bytes per tile, 16-B chunk swizzle: chunk c of row r
    // stored at slot c ^ (r&7)  -> conflict-free b128 frag reads.
    __shared__ __align__(16) unsigned char As[128 * 128];
    __shared__ __align__(16) unsigned char Bs[128 * 128];

    const int tid  = threadIdx.x;
    const int lane = tid & 63;
    const int wave = tid >> 6;
    const int wm   = wave >> 1;        // 2x2 wave grid over the 128x128 tile
    const int wn   = wave & 1;
    const int quad = lane >> 4;
    const int cl   = lane & 15;

    // staging: issue t covers rows wave*32 + t*8 .. +8; lane -> row lane>>3,
    // LDS slot lane&7 (HW: dest = base + lane*16), global chunk = slot ^ (row&7)
    const int sRowOff = lane >> 3;            // 0..7
    const int chunk   = (lane & 7) ^ sRowOff; // (row&7) == sRowOff
    const unsigned char* gA = A + (size_t)(rowTile + wave * 32 + sRowOff) * DIM + chunk * 16;
    const unsigned char* gB = A + (size_t)(colTile + wave * 32 + sRowOff) * DIM + chunk * 16;
    unsigned char* lA = As + wave * 32 * 128 + lane * 16;
    unsigned char* lB = Bs + wave * 32 * 128 + lane * 16;

    floatx4 acc[4][4];
    const floatx4 z4 = {0.f, 0.f, 0.f, 0.f};
    #pragma unroll
    for (int mi = 0; mi < 4; ++mi)
        #pragma unroll
        for (int ni = 0; ni < 4; ++ni) acc[mi][ni] = z4;

    // frag read slots (un-swizzle): lane reads 16-B chunks 2q and 2q+1 of its row
    const int h  = cl & 7;
    const int s0 = ((2 * quad) ^ h) * 16;
    const int s1 = ((2 * quad + 1) ^ h) * 16;
    const unsigned char* aRow = As + (size_t)(wm * 64 + cl) * 128;
    const unsigned char* bRow = Bs + (size_t)(wn * 64 + cl) * 128;

    for (int k0 = 0; k0 < DIM; k0 += 128) {
        __syncthreads();                 // all waves done reading previous tile
        #pragma unroll
        for (int t = 0; t < 4; ++t) {
            async_ld16(gA + (size_t)t * 8 * DIM, lA + t * 1024);
            async_ld16(gB + (size_t)t * 8 * DIM, lB + t * 1024);
        }
        gA += 128; gB += 128;
        __syncthreads();                 // vmcnt drain + all data visible

        intx8 af[4], bf[4];
        #pragma unroll
        for (int mi = 0; mi < 4; ++mi) {
            const unsigned char* r = aRow + mi * 16 * 128;
            intx4 lo = *(const intx4*)(r + s0);
            intx4 hi = *(const intx4*)(r + s1);
            af[mi][0] = lo[0]; af[mi][1] = lo[1]; af[mi][2] = lo[2]; af[mi][3] = lo[3];
            af[mi][4] = hi[0]; af[mi][5] = hi[1]; af[mi][6] = hi[2]; af[mi][7] = hi[3];
        }
        #pragma unroll
        for (int ni = 0; ni < 4; ++ni) {
            const unsigned char* r = bRow + ni * 16 * 128;
            intx4 lo = *(const intx4*)(r + s0);
            intx4 hi = *(const intx4*)(r + s1);
            bf[ni][0] = lo[0]; bf[ni][1] = lo[1]; bf[ni][2] = lo[2]; bf[ni][3] = lo[3];
            bf[ni][4] = hi[0]; bf[ni][5] = hi[1]; bf[ni][6] = hi[2]; bf[ni][7] = hi[3];
        }
        #pragma unroll
        for (int mi = 0; mi < 4; ++mi)
            #pragma unroll
            for (int ni = 0; ni < 4; ++ni)
                acc[mi][ni] = __builtin_amdgcn_mfma_scale_f32_16x16x128_f8f6f4(
                    af[mi], bf[ni], acc[mi][ni],
                    0, 0,                     // cbsz=fp8(e4m3), blgp=fp8(e4m3)
                    0, 0x7F7F7F7F,            // scale_a opsel, scale_a = 2^0
                    0, 0x7F7F7F7F);           // scale_b opsel, scale_b = 2^0
    }

    // ---- epilogue: e = exp(acc * 2/FSCALE^2), eye mask, dual row/col sums ----
    int   colg[4];
    float wRc[4];                        // col label weight (row-part bucket)
    #pragma unroll
    for (int ni = 0; ni < 4; ++ni) {
        colg[ni] = colTile + wn * 64 + ni * 16 + cl;
        wRc[ni]  = (label[colg[ni]] != 0) ? 1.0f : 0.0f;
    }

    float colR[4] = {0.f, 0.f, 0.f, 0.f};
    float colN[4] = {0.f, 0.f, 0.f, 0.f};

    #pragma unroll
    for (int mi = 0; mi < 4; ++mi) {
        const int rowBase = rowTile + wm * 64 + mi * 16 + quad * 4;   // C/D: row=quad*4+reg
        #pragma unroll
        for (int r = 0; r < 4; ++r) {
            const int rowg = rowBase + r;
            const float wRr = (label[rowg] != 0) ? 1.0f : 0.0f;
            float pR = 0.f, pN = 0.f;
            #pragma unroll
            for (int ni = 0; ni < 4; ++ni) {
                float c = acc[mi][ni][r];
                float e = __expf(c * EXPF);
                if (diag) e = (rowg == colg[ni]) ? 0.0f : e;      // eye mask
                pR += wRc[ni] * e;
                pN += (1.0f - wRc[ni]) * e;
                colR[ni] += wRr * e;
                colN[ni] += (1.0f - wRr) * e;
            }
            #pragma unroll
            for (int m = 1; m < 16; m <<= 1) {
                pR += __shfl_xor(pR, m);
                pN += __shfl_xor(pN, m);
            }
            if (cl == 0) {
                atomicAdd(&SR[rowg], pR);
                atomicAdd(&SN[rowg], pN);
            }
        }
    }

    if (!diag) {
        #pragma unroll
        for (int ni = 0; ni < 4; ++ni) {
            float cR = colR[ni], cN = colN[ni];
            cR += __shfl_xor(cR, 16); cN += __shfl_xor(cN, 16);
            cR += __shfl_xor(cR, 32); cN += __shfl_xor(cN, 32);
            if (quad == 0) {
                atomicAdd(&SR[colg[ni]], cR);
                atomicAdd(&SN[colg[ni]], cN);
            }
        }
    }
}

// ---------------- final per-row loss + global reduce ----------------
__global__ __launch_bounds__(256) void loss_kernel(const float* __restrict__ S,
                                                   const int* __restrict__ label,
                                                   float* __restrict__ out) {
    const int i = blockIdx.x * 256 + threadIdx.x;   // 0..8191
    const int lab = label[i];
    float t = 0.f;
    #pragma unroll
    for (int f = 0; f < 2; ++f) {
        const float* SR = S + (size_t)f * 2 * BATCH;
        const float* SN = SR + BATCH;
        const float own = lab ? SR[i] : SN[i];
        const float oth = lab ? SN[i] : SR[i];
        t += -logf(own / (own + oth) + 1e-8f);
    }
    t *= (1.0f / 4096.0f);
    #pragma unroll
    for (int m = 32; m >= 1; m >>= 1) t += __shfl_xor(t, m);
    __shared__ float red[4];
    if ((threadIdx.x & 63) == 0) red[threadIdx.x >> 6] = t;
    __syncthreads();
    if (threadIdx.x == 0) atomicAdd(out, red[0] + red[1] + red[2] + red[3]);
}

extern "C" void kernel_launch(void* const* d_in, const int* in_sizes, int n_in,
                              void* d_out, int out_size, void* d_ws, size_t ws_size,
                              hipStream_t stream) {
    const float* text  = (const float*)d_in[0];
    const float* image = (const float*)d_in[1];
    const int*   label = (const int*)d_in[2];
    float* out = (float*)d_out;

    // workspace: Fn[2][8192][1024] fp8 (16 MB), then S[2][2][8192] f32
    unsigned char* Fn = (unsigned char*)d_ws;
    float* S = (float*)((char*)d_ws + (size_t)2 * BATCH * DIM);

    hipMemsetAsync(S, 0, (size_t)2 * 2 * BATCH * sizeof(float), stream);
    hipMemsetAsync(out, 0, sizeof(float), stream);

    dim3 ngrid(BATCH, 2);
    norm_kernel<<<ngrid, 256, 0, stream>>>(text, image, Fn);

    dim3 grid(GRIDX, 1, 2);
    sim_kernel<<<grid, 256, 0, stream>>>(Fn, label, S);

    loss_kernel<<<BATCH / 256, 256, 0, stream>>>(S, label, out);
}